// Round 16
// baseline (181.097 us; speedup 1.0000x reference)
//
#include <hip/hip_runtime.h>
#include <hip/hip_fp16.h>

#define N_NODES 200000
#define N_EDGES 4000000
#define N_GRAPHS 512
#define D 20
#define OUT 5

#define BSH 6            // final bucket: 64 nodes
#define BN 64
#define NFB 3125         // final buckets = 200000/64 exactly
#define NFBP 3136        // padded = 49*64
#define NCB 49           // coarse buckets: dst>>12 (4096 nodes)
#define NC 500           // chunks for hist/partA
#define CHUNK 8000
#define CH2 7168         // partB chunk (within coarse segment)
#define NCH2 13          // 13*7168 = 93184 >= coarse max (+40 sigma)
#define MAX_EB 1792      // max edges per final bucket (mean 1280, +14 sigma)
#define GMAX 8

// ---------- P1: per-chunk FINAL-bucket histogram; block 0 zeros gsum & bucket_tot ----------
__launch_bounds__(1024)
__global__ void k_hist(const int* __restrict__ dst, int* __restrict__ hist_g,
                       float* __restrict__ gsum, int* __restrict__ bucket_tot) {
    __shared__ int h[NFBP];
    int t = threadIdx.x;
    if (blockIdx.x == 0) {
        for (int j = t; j < N_GRAPHS * D; j += 1024) gsum[j] = 0.f;
        for (int j = t; j < NFBP; j += 1024) bucket_tot[j] = 0;
    }
    for (int j = t; j < NFBP; j += 1024) h[j] = 0;
    __syncthreads();
    int base = blockIdx.x * CHUNK;
    for (int k = t; k < CHUNK; k += 1024) atomicAdd(&h[dst[base + k] >> BSH], 1);
    __syncthreads();
    for (int j = t; j < NFBP; j += 1024) hist_g[blockIdx.x * NFBP + j] = h[j];
}

// ---------- P2: column sums of hist matrix -> bucket_tot ----------
__launch_bounds__(256)
__global__ void k_colsum(const int* __restrict__ hist_g, int* __restrict__ bucket_tot) {
    int col = blockIdx.x * 256 + threadIdx.x;
    if (col >= NFBP) return;
    int r0 = blockIdx.y * 50;
    int sum = 0;
    for (int r = r0; r < r0 + 50; r++) sum += hist_g[r * NFBP + col];
    if (sum) atomicAdd(&bucket_tot[col], sum);
}

// ---------- P3: exclusive scan of bucket totals; init fcursor & coarse cursors ----------
__launch_bounds__(1024)
__global__ void k_scan_tot(const int* __restrict__ bucket_tot, int* __restrict__ bucket_base,
                           int* __restrict__ fcursor, int* __restrict__ ccursorA) {
    __shared__ int ps[1024];
    int t = threadIdx.x;
    int base = t * 4;
    int loc[4];
    int sum = 0;
    #pragma unroll
    for (int j = 0; j < 4; j++) {
        int idx = base + j;
        int x = (idx < NFBP) ? bucket_tot[idx] : 0;
        loc[j] = sum;
        sum += x;
    }
    ps[t] = sum;
    __syncthreads();
    for (int off = 1; off < 1024; off <<= 1) {
        int a = (t >= off) ? ps[t - off] : 0;
        __syncthreads();
        ps[t] += a;
        __syncthreads();
    }
    int carry = (t > 0) ? ps[t - 1] : 0;
    #pragma unroll
    for (int j = 0; j < 4; j++) {
        int idx = base + j;
        if (idx < NFBP) {
            int v = carry + loc[j];
            bucket_base[idx] = v;
            fcursor[idx] = v;
        }
    }
    __syncthreads();
    if (t < NCB) ccursorA[t] = bucket_base[t << 6];
}

// ---------- P4a: coarse partition (49 buckets), cursor-reserved ----------
__launch_bounds__(1024)
__global__ void k_partA(const int* __restrict__ src, const int* __restrict__ dst,
                        int* __restrict__ ccursorA, int* __restrict__ ebufA) {
    __shared__ int h[NCB];
    __shared__ int lcur[NCB];
    int t = threadIdx.x, c = blockIdx.x;
    if (t < NCB) h[t] = 0;
    __syncthreads();
    int base = c * CHUNK;
    for (int k = t; k < CHUNK; k += 1024) atomicAdd(&h[dst[base + k] >> 12], 1);
    __syncthreads();
    if (t < NCB) lcur[t] = atomicAdd(&ccursorA[t], h[t]);
    __syncthreads();
    for (int k = t; k < CHUNK; k += 1024) {
        int d = dst[base + k];
        int sv = src[base + k];
        int cb = d >> 12;
        int pos = atomicAdd(&lcur[cb], 1);
        ebufA[pos] = (sv << 12) | (d & 4095);
    }
}

// ---------- P4b: fine partition within coarse (64 sub-buckets) ----------
__launch_bounds__(1024)
__global__ void k_partB(const int* __restrict__ ebufA, const int* __restrict__ bucket_base,
                        int* __restrict__ fcursor, int* __restrict__ ebuf) {
    int cb = blockIdx.x, j = blockIdx.y, t = threadIdx.x;
    int cbase = bucket_base[cb << 6];
    int cend_idx = (cb + 1) << 6; if (cend_idx > NFB) cend_idx = NFB;
    int cend = bucket_base[cend_idx];
    int lo = cbase + j * CH2;
    int hi = lo + CH2; if (hi > cend) hi = cend;
    if (lo >= hi) return;
    __shared__ int h[64];
    __shared__ int lcur[64];
    if (t < 64) h[t] = 0;
    __syncthreads();
    for (int k = lo + t; k < hi; k += 1024) atomicAdd(&h[(ebufA[k] >> 6) & 63], 1);
    __syncthreads();
    if (t < 64) lcur[t] = atomicAdd(&fcursor[(cb << 6) + t], h[t]);
    __syncthreads();
    for (int k = lo + t; k < hi; k += 1024) {
        int p = ebufA[k];
        int sb = (p >> 6) & 63;
        int pos = atomicAdd(&lcur[sb], 1);
        ebuf[pos] = ((p >> 12) << 6) | (p & 63);       // (src<<6)|dst_local
    }
}

// ---------- P5: per-bucket degree -> offs; SoA f16 slices xhA/xhB/xhC ----------
__launch_bounds__(256)
__global__ void k_count_xh(const int* __restrict__ ebuf, const int* __restrict__ bucket_base,
                           const float4* __restrict__ x4, int* __restrict__ offs_g,
                           uint4* __restrict__ xhA, uint4* __restrict__ xhB,
                           uint2* __restrict__ xhC) {
    __shared__ int cnt[BN];
    __shared__ int s[BN];
    __shared__ float sdi[BN];
    int b = blockIdx.x, t = threadIdx.x;
    int eb = bucket_base[b], ee = bucket_base[b + 1];
    if (t < BN) cnt[t] = 0;
    __syncthreads();
    for (int k = eb + t; k < ee; k += 256) atomicAdd(&cnt[ebuf[k] & (BN - 1)], 1);
    __syncthreads();
    int v = (t < BN) ? cnt[t] : 0;
    if (t < BN) s[t] = v;
    __syncthreads();
    for (int off = 1; off < BN; off <<= 1) {
        int a = 0;
        if (t < BN && t >= off) a = s[t - off];
        __syncthreads();
        if (t < BN) s[t] += a;
        __syncthreads();
    }
    if (t < BN) {
        int node = (b << BSH) + t;
        offs_g[node] = eb + s[t] - v;
        sdi[t] = rsqrtf((float)(v + 1));
    }
    __syncthreads();
    for (int j = t; j < BN * 3; j += 256) {
        int vl = j / 3, q = j - vl * 3;
        int node = (b << BSH) + vl;
        float di = sdi[vl];
        if (q < 2) {
            float4 lo4 = x4[node * 5 + 2 * q];
            float4 hi4 = x4[node * 5 + 2 * q + 1];
            __half2 h0 = __float22half2_rn(make_float2(lo4.x * di, lo4.y * di));
            __half2 h1 = __float22half2_rn(make_float2(lo4.z * di, lo4.w * di));
            __half2 h2 = __float22half2_rn(make_float2(hi4.x * di, hi4.y * di));
            __half2 h3 = __float22half2_rn(make_float2(hi4.z * di, hi4.w * di));
            uint4 u;
            u.x = *(unsigned int*)&h0; u.y = *(unsigned int*)&h1;
            u.z = *(unsigned int*)&h2; u.w = *(unsigned int*)&h3;
            if (q == 0) xhA[node] = u; else xhB[node] = u;
        } else {
            float4 lo4 = x4[node * 5 + 4];
            __half2 h0 = __float22half2_rn(make_float2(lo4.x * di, lo4.y * di));
            __half2 h1 = __float22half2_rn(make_float2(lo4.z * di, lo4.w * di));
            uint2 u;
            u.x = *(unsigned int*)&h0; u.y = *(unsigned int*)&h1;
            xhC[node] = u;
        }
    }
}

// ---------- decode helpers ----------
__device__ __forceinline__ void adds8(float& a0, float& a1, float& a2, float& a3,
                                      float& a4, float& a5, float& a6, float& a7, uint4 m) {
    float2 f0 = __half22float2(*(__half2*)&m.x);
    float2 f1 = __half22float2(*(__half2*)&m.y);
    float2 f2 = __half22float2(*(__half2*)&m.z);
    float2 f3 = __half22float2(*(__half2*)&m.w);
    a0 += f0.x; a1 += f0.y; a2 += f1.x; a3 += f1.y;
    a4 += f2.x; a5 += f2.y; a6 += f3.x; a7 += f3.y;
}
__device__ __forceinline__ void adds4(float& a0, float& a1, float& a2, float& a3, uint2 m) {
    float2 f0 = __half22float2(*(__half2*)&m.x);
    float2 f1 = __half22float2(*(__half2*)&m.y);
    a0 += f0.x; a1 += f0.y; a2 += f1.x; a3 += f1.y;
}

// ---------- P6: gather with 3 sequential SoA slice phases (L2-resident per phase) ----------
__launch_bounds__(256, 6)
__global__ void k_gather_fused(const int* __restrict__ ebuf, const int* __restrict__ bucket_base,
                               const int* __restrict__ offs_g, const uint4* __restrict__ xhA,
                               const uint4* __restrict__ xhB, const uint2* __restrict__ xhC,
                               const int* __restrict__ batch, const float* __restrict__ W1,
                               const float* __restrict__ b1, float* __restrict__ gsum) {
    __shared__ int loff[BN + 1];
    __shared__ int cur[BN];
    __shared__ int lcsr[MAX_EB];
    __shared__ float w[D * D];
    __shared__ float wb[D];
    __shared__ float sagg[BN][21];
    __shared__ float part[4][BN][9];
    __shared__ float lgsum[GMAX][D];
    int b = blockIdx.x, t = threadIdx.x;
    int eb = bucket_base[b], ee = bucket_base[b + 1];
    int n = ee - eb;

    for (int j = t; j < D * D; j += 256) w[j] = W1[j];
    if (t < D) wb[t] = b1[t];
    if (t < GMAX * D) ((float*)lgsum)[t] = 0.f;
    if (t < BN) {
        int o = offs_g[(b << BSH) + t] - eb;
        loff[t] = o;
        cur[t] = o;
    }
    if (t == 0) loff[BN] = n;
    __syncthreads();

    // build bucket CSR in LDS
    for (int k = t; k < n; k += 256) {
        int p = ebuf[eb + k];
        int pos = atomicAdd(&cur[p & (BN - 1)], 1);
        if (pos < MAX_EB) lcsr[pos] = p >> BSH;
    }
    __syncthreads();

    int vl = t & 63;
    int sg = t >> 6;                         // 4 interleaved k-segments per node
    int node = (b << BSH) + vl;
    int lo0 = loff[vl], hi0 = loff[vl + 1];
    if (hi0 > MAX_EB) hi0 = MAX_EB;
    if (lo0 > MAX_EB) lo0 = MAX_EB;

    // ---- phase A: dims 0-7 (xhA hot, 3.2MB) ----
    {
        float a0=0,a1=0,a2=0,a3=0,a4=0,a5=0,a6=0,a7=0;
        if (sg == 0) adds8(a0,a1,a2,a3,a4,a5,a6,a7, xhA[node]);   // self term
        int k = lo0 + sg;
        for (; k + 12 < hi0; k += 16) {
            int s0 = lcsr[k], s1 = lcsr[k + 4], s2 = lcsr[k + 8], s3 = lcsr[k + 12];
            uint4 m0 = xhA[s0];
            uint4 m1 = xhA[s1];
            uint4 m2 = xhA[s2];
            uint4 m3 = xhA[s3];
            adds8(a0,a1,a2,a3,a4,a5,a6,a7, m0);
            adds8(a0,a1,a2,a3,a4,a5,a6,a7, m1);
            adds8(a0,a1,a2,a3,a4,a5,a6,a7, m2);
            adds8(a0,a1,a2,a3,a4,a5,a6,a7, m3);
        }
        for (; k < hi0; k += 4) adds8(a0,a1,a2,a3,a4,a5,a6,a7, xhA[lcsr[k]]);
        part[sg][vl][0]=a0; part[sg][vl][1]=a1; part[sg][vl][2]=a2; part[sg][vl][3]=a3;
        part[sg][vl][4]=a4; part[sg][vl][5]=a5; part[sg][vl][6]=a6; part[sg][vl][7]=a7;
    }
    __syncthreads();
    for (int j = t; j < BN * 8; j += 256) {
        int d = j & 7, v = j >> 3;
        sagg[v][d] = part[0][v][d] + part[1][v][d] + part[2][v][d] + part[3][v][d];
    }
    __syncthreads();

    // ---- phase B: dims 8-15 (xhB hot) ----
    {
        float a0=0,a1=0,a2=0,a3=0,a4=0,a5=0,a6=0,a7=0;
        if (sg == 0) adds8(a0,a1,a2,a3,a4,a5,a6,a7, xhB[node]);
        int k = lo0 + sg;
        for (; k + 12 < hi0; k += 16) {
            int s0 = lcsr[k], s1 = lcsr[k + 4], s2 = lcsr[k + 8], s3 = lcsr[k + 12];
            uint4 m0 = xhB[s0];
            uint4 m1 = xhB[s1];
            uint4 m2 = xhB[s2];
            uint4 m3 = xhB[s3];
            adds8(a0,a1,a2,a3,a4,a5,a6,a7, m0);
            adds8(a0,a1,a2,a3,a4,a5,a6,a7, m1);
            adds8(a0,a1,a2,a3,a4,a5,a6,a7, m2);
            adds8(a0,a1,a2,a3,a4,a5,a6,a7, m3);
        }
        for (; k < hi0; k += 4) adds8(a0,a1,a2,a3,a4,a5,a6,a7, xhB[lcsr[k]]);
        part[sg][vl][0]=a0; part[sg][vl][1]=a1; part[sg][vl][2]=a2; part[sg][vl][3]=a3;
        part[sg][vl][4]=a4; part[sg][vl][5]=a5; part[sg][vl][6]=a6; part[sg][vl][7]=a7;
    }
    __syncthreads();
    for (int j = t; j < BN * 8; j += 256) {
        int d = j & 7, v = j >> 3;
        sagg[v][8 + d] = part[0][v][d] + part[1][v][d] + part[2][v][d] + part[3][v][d];
    }
    __syncthreads();

    // ---- phase C: dims 16-19 (xhC hot, 1.6MB) ----
    {
        float c0=0,c1=0,c2=0,c3=0;
        if (sg == 0) adds4(c0,c1,c2,c3, xhC[node]);
        int k = lo0 + sg;
        for (; k + 12 < hi0; k += 16) {
            int s0 = lcsr[k], s1 = lcsr[k + 4], s2 = lcsr[k + 8], s3 = lcsr[k + 12];
            uint2 m0 = xhC[s0];
            uint2 m1 = xhC[s1];
            uint2 m2 = xhC[s2];
            uint2 m3 = xhC[s3];
            adds4(c0,c1,c2,c3, m0);
            adds4(c0,c1,c2,c3, m1);
            adds4(c0,c1,c2,c3, m2);
            adds4(c0,c1,c2,c3, m3);
        }
        for (; k < hi0; k += 4) adds4(c0,c1,c2,c3, xhC[lcsr[k]]);
        part[sg][vl][0]=c0; part[sg][vl][1]=c1; part[sg][vl][2]=c2; part[sg][vl][3]=c3;
    }
    __syncthreads();
    for (int j = t; j < BN * 4; j += 256) {
        int d = j & 3, v = j >> 2;
        sagg[v][16 + d] = part[0][v][d] + part[1][v][d] + part[2][v][d] + part[3][v][d];
    }
    __syncthreads();

    // ---- matvec + relu + pool ----
    int g0 = batch[b << BSH];
    int glast = batch[(b << BSH) + BN - 1];
    int gcnt = glast - g0 + 1;

    if (t < BN) {
        float di = rsqrtf((float)(loff[t + 1] - loff[t] + 1));
        int gi = batch[(b << BSH) + t] - g0;
        float pre[D];
        #pragma unroll
        for (int d = 0; d < D; d++) pre[d] = sagg[t][d];
        int t20 = t % D;
        bool fits = (gcnt <= GMAX);
        for (int jj = 0; jj < D; jj++) {
            int o = t20 + jj; if (o >= D) o -= D;
            float h = 0.f;
            #pragma unroll
            for (int d = 0; d < D; d++) h = fmaf(pre[d], w[d * D + o], h);
            h = fmaf(h, di, wb[o]);
            h = fmaxf(h, 0.f);
            if (fits) atomicAdd(&lgsum[gi][o], h);
            else atomicAdd(&gsum[(g0 + gi) * D + o], h);  // safety path
        }
    }
    __syncthreads();
    if (gcnt <= GMAX && t < gcnt * D) {
        atomicAdd(&gsum[(g0 + t / D) * D + (t % D)], lgsum[t / D][t % D]);
    }
}

// ---------- P7: head: mean -> W_out -> softmax ----------
__launch_bounds__(64)
__global__ void k_head(const float* __restrict__ gsum, const int* __restrict__ batch,
                       const float* __restrict__ W_out, const float* __restrict__ b_out,
                       float* __restrict__ out) {
    __shared__ float wo[D * OUT];
    __shared__ float bo[OUT];
    int t = threadIdx.x;
    for (int j = t; j < D * OUT; j += 64) wo[j] = W_out[j];
    if (t < OUT) bo[t] = b_out[t];
    __syncthreads();
    int g = blockIdx.x * 64 + t;
    if (g >= N_GRAPHS) return;
    auto lb = [&](int key) {
        int lo = 0, hi = N_NODES;
        while (lo < hi) { int mid = (lo + hi) >> 1; if (batch[mid] < key) lo = mid + 1; else hi = mid; }
        return lo;
    };
    int cnt = lb(g + 1) - lb(g);
    float inv = 1.0f / fmaxf((float)cnt, 1.0f);
    float logits[OUT];
    #pragma unroll
    for (int o = 0; o < OUT; o++) logits[o] = bo[o];
    #pragma unroll
    for (int d = 0; d < D; d++) {
        float p = gsum[g * D + d] * inv;
        #pragma unroll
        for (int o = 0; o < OUT; o++) logits[o] = fmaf(p, wo[d * OUT + o], logits[o]);
    }
    float m = logits[0];
    #pragma unroll
    for (int o = 1; o < OUT; o++) m = fmaxf(m, logits[o]);
    float ex[OUT], sum = 0.f;
    #pragma unroll
    for (int o = 0; o < OUT; o++) { ex[o] = __expf(logits[o] - m); sum += ex[o]; }
    float isum = 1.0f / sum;
    #pragma unroll
    for (int o = 0; o < OUT; o++) out[g * OUT + o] = ex[o] * isum;
}

extern "C" void kernel_launch(void* const* d_in, const int* in_sizes, int n_in,
                              void* d_out, int out_size, void* d_ws, size_t ws_size,
                              hipStream_t stream) {
    const float* x     = (const float*)d_in[0];
    const int*   edge  = (const int*)d_in[1];
    const int*   batch = (const int*)d_in[2];
    const float* W1    = (const float*)d_in[3];
    const float* b1    = (const float*)d_in[4];
    const float* W_out = (const float*)d_in[5];
    const float* b_out = (const float*)d_in[6];
    float* out = (float*)d_out;

    const int* src = edge;
    const int* dst = edge + N_EDGES;
    char* ws = (char*)d_ws;

    // workspace layout (bytes), total ~47.2 MB (ws >= 50.4 MB proven in R3):
    int*   hist_g      = (int*)(ws);                  // 500*3136*4 = 6,272,000
    int*   bucket_tot  = (int*)(ws + 6272000);        // 3136*4
    int*   bucket_base = (int*)(ws + 6284544);        // 3136*4
    int*   fcursor     = (int*)(ws + 6297088);        // 3136*4
    int*   ccursorA    = (int*)(ws + 6309632);        // 64*4
    float* gsum        = (float*)(ws + 6309888);      // 512*20*4
    int*   offs_g      = (int*)(ws + 6350848);        // 800,000
    uint4* xhA         = (uint4*)(ws + 7150848);      // 3,200,000 (dims 0-7)
    uint4* xhB         = (uint4*)(ws + 10350848);     // 3,200,000 (dims 8-15)
    uint2* xhC         = (uint2*)(ws + 13550848);     // 1,600,000 (dims 16-19)
    int*   ebufA       = (int*)(ws + 15150848);       // 16,000,000
    int*   ebuf        = (int*)(ws + 31150848);       // 16,000,000

    k_hist<<<NC, 1024, 0, stream>>>(dst, hist_g, gsum, bucket_tot);
    k_colsum<<<dim3(13, 10), 256, 0, stream>>>(hist_g, bucket_tot);
    k_scan_tot<<<1, 1024, 0, stream>>>(bucket_tot, bucket_base, fcursor, ccursorA);
    k_partA<<<NC, 1024, 0, stream>>>(src, dst, ccursorA, ebufA);
    k_partB<<<dim3(NCB, NCH2), 1024, 0, stream>>>(ebufA, bucket_base, fcursor, ebuf);
    k_count_xh<<<NFB, 256, 0, stream>>>(ebuf, bucket_base, (const float4*)x, offs_g,
                                        xhA, xhB, xhC);
    k_gather_fused<<<NFB, 256, 0, stream>>>(ebuf, bucket_base, offs_g, xhA, xhB, xhC,
                                            batch, W1, b1, gsum);
    k_head<<<(N_GRAPHS + 63) / 64, 64, 0, stream>>>(gsum, batch, W_out, b_out, out);
}